// Round 13
// baseline (123.004 us; speedup 1.0000x reference)
//
#include <hip/hip_runtime.h>

// out[d] = sum_{e: dst[e]==d} x[src[e]]   (N=100k, E=1.6M, D=32 f32)
//
// Round-12 lesson: shrinking buckets inflates the cnt matrix every gather
// block re-scans -> regression. Keep round-11 gather (128-node buckets,
// 512 thr). Round 13: scatter occupancy 2x via CAP 16->8 (LDS stage 50->28KB,
// 5 blocks/CU allowed) and NSUB 512->1024 blocks; cooperative overflow
// replay (lam=2 -> ~160 overflows expected, compacted in parallel).

#define D_FEAT 32
#define BKT_SHIFT 7
#define BKT_NODES 128
#define CAPSH 3               // 8 slots per sub-bin (32B)
#define CAP (1 << CAPSH)
#define ECAP 4096             // packed entries per gather window
#define NSUB 1024             // scatter blocks (= sub-bins per bucket)
#define OVFB 512              // overflow pairs per scatter block
typedef unsigned int u32;

// One block per edge-chunk. Stage sub-bins in LDS, gated bucket-major flush.
// dynamic LDS: s_stage[nb*CAP] | s_cur[nb]  (~28 KB @ nb=782)
__global__ void __launch_bounds__(512)
k_scatter7(const int* __restrict__ src, const int* __restrict__ dst,
           u32* __restrict__ cnt, u32* __restrict__ bin,
           u32* __restrict__ ovfb, u32* __restrict__ ovfn,
           int n_edges, int nb, int chunk) {
    extern __shared__ u32 smem[];
    u32* s_stage = smem;                           // nb*CAP words
    u32* s_cur   = smem + ((size_t)nb << CAPSH);   // nb words
    __shared__ u32 s_ovf_n;
    int blk = blockIdx.x, t = threadIdx.x;
    for (int i = t; i < nb; i += 512) s_cur[i] = 0u;
    if (t == 0) s_ovf_n = 0u;
    __syncthreads();
    int beg = blk * chunk, end = min(beg + chunk, n_edges);
    for (int e = beg + t; e < end; e += 512) {
        u32 d = (u32)dst[e];
        u32 b = d >> BKT_SHIFT;
        u32 pos = atomicAdd(&s_cur[b], 1u);          // LDS-only RMW
        u32 packed = (u32)src[e] | ((d & (BKT_NODES - 1)) << 17);
        if (pos < (u32)CAP) {
            s_stage[(b << CAPSH) + pos] = packed;
        } else {
            u32 g = atomicAdd(&s_ovf_n, 1u);         // rare: ~160 total @ lam=2
            if (g < (u32)OVFB) {
                ovfb[((size_t)blk * OVFB + g) * 2]     = packed;
                ovfb[((size_t)blk * OVFB + g) * 2 + 1] = (u32)b;
            }
        }
    }
    __syncthreads();
    // gated bucket-major flush: bin[b][blk][slot]; CAP=8 -> 2 quads/bucket
    {
        const uint4* sq = (const uint4*)s_stage;
        uint4* gq = (uint4*)bin;
        int nquads = nb << (CAPSH - 2);
        for (int i = t; i < nquads; i += 512) {
            int b  = i >> (CAPSH - 2);
            int k4 = i & ((1 << (CAPSH - 2)) - 1);
            u32 cn = min(s_cur[b], (u32)CAP);
            if ((u32)(k4 << 2) < cn)
                gq[(((size_t)b * NSUB + blk) << (CAPSH - 2)) + k4] = sq[i];
        }
    }
    u32* row = cnt + (size_t)blk * nb;
    for (int i = t; i < nb; i += 512) row[i] = min(s_cur[i], (u32)CAP);
    if (t == 0) ovfn[blk] = min(s_ovf_n, (u32)OVFB);
}

// One block per 128-node bucket, 512 threads (round-11 body; nsub=1024 via
// pair-scan). counts -> shfl scan -> gated sequential pack -> sort by dlocal
// -> register accumulate (4-way unrolled) -> cooperative overflow replay.
__global__ void __launch_bounds__(512)
k_gather7(const float* __restrict__ x, const u32* __restrict__ cnt,
          const u32* __restrict__ bin, const u32* __restrict__ ovfb,
          const u32* __restrict__ ovfn, float* __restrict__ out,
          int n_nodes, int nb) {
    __shared__ u32 s_cnt[NSUB];
    __shared__ u32 s_base[NSUB + 1];
    __shared__ u32 s_wsum[8];
    __shared__ u32 s_ent[ECAP];
    __shared__ u32 s_srt[ECAP];
    __shared__ u32 s_off[BKT_NODES + 1];
    __shared__ u32 s_cur[BKT_NODES];
    __shared__ u32 s_has;
    __shared__ u32 s_rn;
    int b = blockIdx.x, t = threadIdx.x;
    int lane = t & 63, wid = t >> 6;       // 8 waves
    int node0 = b * BKT_NODES;
    const float4* x4 = (const float4*)x;
    const uint4* bin4 = (const uint4*)bin;
    int q = t & 7;
    int n0 = t >> 3;                       // nodes n0 (0..63) and n0+64
    float4 a0 = make_float4(0.f, 0.f, 0.f, 0.f);
    float4 a1 = make_float4(0.f, 0.f, 0.f, 0.f);

    // sub-bin counts (2/thread) + shfl pair-scan across 8 waves
    u32 c0 = min(cnt[(size_t)(2 * t) * nb + b], (u32)CAP);
    u32 c1 = min(cnt[(size_t)(2 * t + 1) * nb + b], (u32)CAP);
    u32 ov = ovfn[2 * t] | ovfn[2 * t + 1];
    s_cnt[2 * t] = c0;
    s_cnt[2 * t + 1] = c1;
    if (t == 0) { s_has = 0u; s_rn = 0u; }
    u32 pair = c0 + c1;
    u32 s = pair;
    #pragma unroll
    for (int off = 1; off < 64; off <<= 1) {
        u32 y = __shfl_up(s, off, 64);
        if (lane >= off) s += y;
    }
    if (lane == 63) s_wsum[wid] = s;
    __syncthreads();
    if (t == 0) {
        u32 run = 0u;
        #pragma unroll
        for (int w = 0; w < 8; ++w) { u32 v = s_wsum[w]; s_wsum[w] = run; run += v; }
    }
    if (ov) atomicOr(&s_has, 1u);
    __syncthreads();
    u32 incl = s + s_wsum[wid];
    s_base[2 * t] = incl - pair;
    s_base[2 * t + 1] = incl - c1;
    if (t == 511) s_base[NSUB] = incl;
    __syncthreads();

    int subA = 0;
    u32 baseA = 0u;
    while (subA < NSUB) {
        int lo = subA + 1, hi = NSUB;
        while (lo < hi) {
            int mid = (lo + hi + 1) >> 1;
            if (s_base[mid] - baseA <= (u32)ECAP) lo = mid; else hi = mid - 1;
        }
        int subB = lo;
        int m = (int)(s_base[subB] - baseA);

        // gated sequential pack: 2 quads per sub-bin
        {
            int quads = (subB - subA) << (CAPSH - 2);
            size_t qbase = ((size_t)b * NSUB + subA) << (CAPSH - 2);
            for (int i = t; i < quads; i += 512) {
                int sub = subA + (i >> (CAPSH - 2));
                int slot0 = (i & ((1 << (CAPSH - 2)) - 1)) << 2;
                u32 cn = s_cnt[sub];
                if ((u32)slot0 < cn) {
                    uint4 v = bin4[qbase + i];
                    u32 base = (s_base[sub] - baseA) + slot0;
                    s_ent[base] = v.x;
                    if ((u32)(slot0 + 1) < cn) s_ent[base + 1] = v.y;
                    if ((u32)(slot0 + 2) < cn) s_ent[base + 2] = v.z;
                    if ((u32)(slot0 + 3) < cn) s_ent[base + 3] = v.w;
                }
            }
        }
        if (t < BKT_NODES) s_cur[t] = 0u;
        __syncthreads();

        // count by dlocal
        for (int i = t; i < m; i += 512) atomicAdd(&s_cur[s_ent[i] >> 17], 1u);
        __syncthreads();

        // 128-entry exclusive scan by wave 0 (2 entries/lane, shfl)
        if (wid == 0) {
            u32 v0 = s_cur[2 * lane], v1 = s_cur[2 * lane + 1];
            u32 ps = v0 + v1;
            #pragma unroll
            for (int off = 1; off < 64; off <<= 1) {
                u32 y = __shfl_up(ps, off, 64);
                if (lane >= off) ps += y;
            }
            u32 ex = ps - (v0 + v1);
            s_off[2 * lane] = ex;          s_cur[2 * lane] = ex;
            s_off[2 * lane + 1] = ex + v0; s_cur[2 * lane + 1] = ex + v0;
            if (lane == 63) s_off[BKT_NODES] = ps;
        }
        __syncthreads();

        // rank into s_srt
        for (int i = t; i < m; i += 512) {
            u32 p = s_ent[i];
            u32 pos = atomicAdd(&s_cur[p >> 17], 1u);
            s_srt[pos] = p & 0x1FFFFu;
        }
        __syncthreads();

        // accumulate: 8 lanes share one 128B x-row; 4-way unroll for MLP
        {
            u32 j = s_off[n0], j1 = s_off[n0 + 1];
            for (; j + 3 < j1; j += 4) {
                float4 xa = x4[(size_t)s_srt[j] * 8 + q];
                float4 xb = x4[(size_t)s_srt[j + 1] * 8 + q];
                float4 xc = x4[(size_t)s_srt[j + 2] * 8 + q];
                float4 xd = x4[(size_t)s_srt[j + 3] * 8 + q];
                a0.x += xa.x + xb.x + xc.x + xd.x;
                a0.y += xa.y + xb.y + xc.y + xd.y;
                a0.z += xa.z + xb.z + xc.z + xd.z;
                a0.w += xa.w + xb.w + xc.w + xd.w;
            }
            for (; j < j1; ++j) {
                float4 xa = x4[(size_t)s_srt[j] * 8 + q];
                a0.x += xa.x; a0.y += xa.y; a0.z += xa.z; a0.w += xa.w;
            }
            j = s_off[n0 + 64]; j1 = s_off[n0 + 65];
            for (; j + 3 < j1; j += 4) {
                float4 xa = x4[(size_t)s_srt[j] * 8 + q];
                float4 xb = x4[(size_t)s_srt[j + 1] * 8 + q];
                float4 xc = x4[(size_t)s_srt[j + 2] * 8 + q];
                float4 xd = x4[(size_t)s_srt[j + 3] * 8 + q];
                a1.x += xa.x + xb.x + xc.x + xd.x;
                a1.y += xa.y + xb.y + xc.y + xd.y;
                a1.z += xa.z + xb.z + xc.z + xd.z;
                a1.w += xa.w + xb.w + xc.w + xd.w;
            }
            for (; j < j1; ++j) {
                float4 xa = x4[(size_t)s_srt[j] * 8 + q];
                a1.x += xa.x; a1.y += xa.y; a1.z += xa.z; a1.w += xa.w;
            }
        }
        __syncthreads();
        subA = subB;
        baseA = s_base[subB];
    }

    // cooperative overflow replay: compact matching pairs into s_ent, process
    if (s_has) {
        for (int sub = 2 * t; sub < NSUB + 2 * t; ) {   // 2 subs per thread
            int s0 = 2 * t, s1 = 2 * t + 1;
            u32 n0c = ovfn[s0], n1c = ovfn[s1];
            for (u32 i = 0; i < n0c; ++i) {
                u32 ob = ovfb[((size_t)s0 * OVFB + i) * 2 + 1];
                if (ob == (u32)b) {
                    u32 pos = atomicAdd(&s_rn, 1u);
                    if (pos < (u32)ECAP) s_ent[pos] = ovfb[((size_t)s0 * OVFB + i) * 2];
                }
            }
            for (u32 i = 0; i < n1c; ++i) {
                u32 ob = ovfb[((size_t)s1 * OVFB + i) * 2 + 1];
                if (ob == (u32)b) {
                    u32 pos = atomicAdd(&s_rn, 1u);
                    if (pos < (u32)ECAP) s_ent[pos] = ovfb[((size_t)s1 * OVFB + i) * 2];
                }
            }
            break;
        }
        __syncthreads();
        u32 rn = min(s_rn, (u32)ECAP);
        for (u32 i = 0; i < rn; ++i) {
            u32 p = s_ent[i];
            u32 dl = p >> 17;
            if (dl == (u32)n0 || dl == (u32)(n0 + 64)) {
                float4 xv = x4[(size_t)(p & 0x1FFFFu) * 8 + q];
                if (dl == (u32)n0) { a0.x += xv.x; a0.y += xv.y; a0.z += xv.z; a0.w += xv.w; }
                else               { a1.x += xv.x; a1.y += xv.y; a1.z += xv.z; a1.w += xv.w; }
            }
        }
    }

    float4* o4 = (float4*)out;
    if (node0 + n0 < n_nodes)      o4[(size_t)node0 * 8 + t] = a0;
    if (node0 + n0 + 64 < n_nodes) o4[(size_t)node0 * 8 + 512 + t] = a1;
}

// ---------------- fallback (round-1 atomic path) ----------------

__global__ void __launch_bounds__(256)
mp_zero_kernel(float* __restrict__ out, int n) {
    int i = blockIdx.x * blockDim.x + threadIdx.x;
    if (i < n) out[i] = 0.0f;
}

__global__ void __launch_bounds__(256)
mp_scatter_kernel(const float* __restrict__ x, const int* __restrict__ src,
                  const int* __restrict__ dst, float* __restrict__ out,
                  int n_edges) {
    int idx = blockIdx.x * blockDim.x + threadIdx.x;
    if (idx >= n_edges * 8) return;
    int e = idx >> 3;
    int c = idx & 7;
    const float4 v = *reinterpret_cast<const float4*>(x + (size_t)src[e] * D_FEAT + c * 4);
    float* o = out + (size_t)dst[e] * D_FEAT + c * 4;
    unsafeAtomicAdd(o + 0, v.x);
    unsafeAtomicAdd(o + 1, v.y);
    unsafeAtomicAdd(o + 2, v.z);
    unsafeAtomicAdd(o + 3, v.w);
}

// ==================== launch ====================

extern "C" void kernel_launch(void* const* d_in, const int* in_sizes, int n_in,
                              void* d_out, int out_size, void* d_ws, size_t ws_size,
                              hipStream_t stream) {
    const float* x = (const float*)d_in[0];
    const int* edge_index = (const int*)d_in[1];
    int n_edges = in_sizes[1] / 2;
    const int* src = edge_index;            // row 0: source j
    const int* dst = edge_index + n_edges;  // row 1: target i
    float* out = (float*)d_out;
    int n_nodes = out_size / D_FEAT;

    int nb = (n_nodes + BKT_NODES - 1) >> BKT_SHIFT;     // 782

    // dynamic LDS for scatter: nb*CAP stage + nb cursors (~28 KB)
    size_t sc_lds = ((size_t)nb * CAP + nb) * sizeof(u32);

    size_t need = ((size_t)NSUB * nb                      // cnt
                   + NSUB                                 // ovfn
                   + 2 * (size_t)NSUB * OVFB              // ovfb
                   + (((size_t)nb * NSUB) << CAPSH))      // bin (bucket-major)
                  * sizeof(u32);

    if (n_nodes <= (1 << 17) && sc_lds <= 64 * 1024 && need <= ws_size) {
        int chunk = (n_edges + NSUB - 1) / NSUB;

        u32* cnt  = (u32*)d_ws;
        u32* ovfn = cnt + (size_t)NSUB * nb;
        u32* ovfb = ovfn + NSUB;
        u32* bin  = ovfb + 2 * (size_t)NSUB * OVFB;

        k_scatter7<<<NSUB, 512, sc_lds, stream>>>(src, dst, cnt, bin, ovfb, ovfn,
                                                  n_edges, nb, chunk);
        k_gather7<<<nb, 512, 0, stream>>>(x, cnt, bin, ovfb, ovfn, out,
                                          n_nodes, nb);
        return;
    }

    // last-resort: atomic path
    mp_zero_kernel<<<(out_size + 255) / 256, 256, 0, stream>>>(out, out_size);
    int total_thr = n_edges * 8;
    mp_scatter_kernel<<<(total_thr + 255) / 256, 256, 0, stream>>>(x, src, dst, out, n_edges);
}

// Round 14
// 116.353 us; speedup vs baseline: 1.0572x; 1.0572x over previous
//
#include <hip/hip_runtime.h>

// out[d] = sum_{e: dst[e]==d} x[src[e]]   (N=100k, E=1.6M, D=32 f32)
//
// Round-13 lesson: gather LDS crossed 40KB -> 3 blocks/CU (was 4) -> 123us.
// This is the exact round-11 champion config (112.4us): 128-node buckets,
// NSUB=512 scatter blocks staging sub-bins in LDS with gated coalesced flush,
// gather at exactly 40KB LDS (4 blocks/CU), shfl scans, 4-way unrolled
// register accumulate. Budget at this config: ~43us harness ws-fill (fixed)
// + ~39 gather + ~23 scatter + gaps.

#define D_FEAT 32
#define BKT_SHIFT 7
#define BKT_NODES 128
#define CAPSH 4               // 16 slots per sub-bin (64B = 1 line)
#define CAP (1 << CAPSH)
#define ECAP 4096             // packed entries per gather flush
#define OVFB 512              // overflow pairs per scatter block
typedef unsigned int u32;

// One block per edge-chunk. Stage sub-bins in LDS, gated bucket-major flush.
// dynamic LDS: s_stage[nb*CAP] | s_cur[nb]
__global__ void __launch_bounds__(512)
k_scatter5(const int* __restrict__ src, const int* __restrict__ dst,
           u32* __restrict__ cnt, u32* __restrict__ bin,
           u32* __restrict__ ovfb, u32* __restrict__ ovfn,
           int n_edges, int nb, int nsub, int chunk) {
    extern __shared__ u32 smem[];
    u32* s_stage = smem;                           // nb*CAP words
    u32* s_cur   = smem + ((size_t)nb << CAPSH);   // nb words
    __shared__ u32 s_ovf_n;
    int blk = blockIdx.x, t = threadIdx.x;
    for (int i = t; i < nb; i += 512) s_cur[i] = 0u;
    if (t == 0) s_ovf_n = 0u;
    __syncthreads();
    int beg = blk * chunk, end = min(beg + chunk, n_edges);
    for (int e = beg + t; e < end; e += 512) {
        u32 d = (u32)dst[e];
        u32 b = d >> BKT_SHIFT;
        u32 pos = atomicAdd(&s_cur[b], 1u);          // LDS-only RMW
        u32 packed = (u32)src[e] | ((d & (BKT_NODES - 1)) << 17);
        if (pos < (u32)CAP) {
            s_stage[(b << CAPSH) + pos] = packed;
        } else {
            u32 g = atomicAdd(&s_ovf_n, 1u);         // ~never taken
            if (g < (u32)OVFB) {
                ovfb[((size_t)blk * OVFB + g) * 2]     = packed;
                ovfb[((size_t)blk * OVFB + g) * 2 + 1] = (u32)b;
            }
        }
    }
    __syncthreads();
    // gated bucket-major flush: bin[b][blk][slot]; only quads with data
    {
        const uint4* sq = (const uint4*)s_stage;
        uint4* gq = (uint4*)bin;
        int nquads = nb << (CAPSH - 2);
        for (int i = t; i < nquads; i += 512) {
            int b  = i >> (CAPSH - 2);
            int k4 = i & ((1 << (CAPSH - 2)) - 1);
            u32 cn = min(s_cur[b], (u32)CAP);
            if ((u32)(k4 << 2) < cn)
                gq[(((size_t)b * nsub + blk) << (CAPSH - 2)) + k4] = sq[i];
        }
    }
    u32* row = cnt + (size_t)blk * nb;
    for (int i = t; i < nb; i += 512) row[i] = min(s_cur[i], (u32)CAP);
    if (t == 0) ovfn[blk] = min(s_ovf_n, (u32)OVFB);
}

// One block per bucket: counts -> shfl-scan -> sequential gated pack ->
// sort by dlocal (shfl-scan) -> register accumulate (4-way unrolled).
__global__ void __launch_bounds__(512)
k_gather5(const float* __restrict__ x, const u32* __restrict__ cnt,
          const u32* __restrict__ bin, const u32* __restrict__ ovfb,
          const u32* __restrict__ ovfn, float* __restrict__ out,
          int n_nodes, int nb, int nsub) {
    __shared__ u32 s_cnt[512];
    __shared__ u32 s_base[513];
    __shared__ u32 s_wsum[8];
    __shared__ u32 s_ent[ECAP];
    __shared__ u32 s_srt[ECAP];
    __shared__ u32 s_off[BKT_NODES + 1];
    __shared__ u32 s_cur[BKT_NODES];
    __shared__ u32 s_has;
    int b = blockIdx.x, t = threadIdx.x;
    int lane = t & 63, wid = t >> 6;
    int node0 = b * BKT_NODES;
    const float4* x4 = (const float4*)x;
    const uint4* bin4 = (const uint4*)bin;
    int q = t & 7;
    int n0 = t >> 3;                       // nodes n0 and n0+64
    float4 a0 = make_float4(0.f, 0.f, 0.f, 0.f);
    float4 a1 = make_float4(0.f, 0.f, 0.f, 0.f);

    // sub-bin counts + exclusive scan (wave shfl + cross-wave fix)
    u32 c = (t < nsub) ? min(cnt[(size_t)t * nb + b], (u32)CAP) : 0u;
    u32 myovf = (t < nsub) ? ovfn[t] : 0u;
    s_cnt[t] = c;
    if (t == 0) s_has = 0u;
    u32 s = c;
    #pragma unroll
    for (int off = 1; off < 64; off <<= 1) {
        u32 y = __shfl_up(s, off, 64);
        if (lane >= off) s += y;
    }
    if (lane == 63) s_wsum[wid] = s;
    __syncthreads();
    if (t == 0) {
        u32 run = 0u;
        #pragma unroll
        for (int w = 0; w < 8; ++w) { u32 v = s_wsum[w]; s_wsum[w] = run; run += v; }
    }
    if (myovf) atomicOr(&s_has, 1u);
    __syncthreads();
    u32 incl = s + s_wsum[wid];
    s_base[t] = incl - c;                  // exclusive
    if (t == 511) s_base[512] = incl;
    __syncthreads();

    int subA = 0;
    u32 baseA = 0u;
    while (subA < nsub) {
        // largest subB with base[subB]-baseA <= ECAP
        int lo = subA + 1, hi = nsub;
        while (lo < hi) {
            int mid = (lo + hi + 1) >> 1;
            if (s_base[mid] - baseA <= (u32)ECAP) lo = mid; else hi = mid - 1;
        }
        int subB = lo;
        int m = (int)(s_base[subB] - baseA);

        // pack sub-bins [subA,subB): sequential gated uint4 stream
        {
            int quads = (subB - subA) << (CAPSH - 2);
            size_t qbase = ((size_t)b * nsub + subA) << (CAPSH - 2);
            for (int i = t; i < quads; i += 512) {
                int sub = subA + (i >> (CAPSH - 2));
                int slot0 = (i & ((1 << (CAPSH - 2)) - 1)) << 2;
                u32 cn = s_cnt[sub];
                if ((u32)slot0 < cn) {
                    uint4 v = bin4[qbase + i];
                    u32 base = (s_base[sub] - baseA) + slot0;
                    s_ent[base] = v.x;
                    if ((u32)(slot0 + 1) < cn) s_ent[base + 1] = v.y;
                    if ((u32)(slot0 + 2) < cn) s_ent[base + 2] = v.z;
                    if ((u32)(slot0 + 3) < cn) s_ent[base + 3] = v.w;
                }
            }
        }
        if (t < BKT_NODES) s_cur[t] = 0u;
        __syncthreads();

        // count by dlocal
        for (int i = t; i < m; i += 512) atomicAdd(&s_cur[s_ent[i] >> 17], 1u);
        __syncthreads();

        // 128-entry exclusive scan by wave 0 (2 entries/lane, shfl)
        if (wid == 0) {
            u32 v0 = s_cur[2 * lane], v1 = s_cur[2 * lane + 1];
            u32 ps = v0 + v1;
            #pragma unroll
            for (int off = 1; off < 64; off <<= 1) {
                u32 y = __shfl_up(ps, off, 64);
                if (lane >= off) ps += y;
            }
            u32 ex = ps - (v0 + v1);
            s_off[2 * lane] = ex;     s_cur[2 * lane] = ex;
            s_off[2 * lane + 1] = ex + v0; s_cur[2 * lane + 1] = ex + v0;
            if (lane == 63) s_off[BKT_NODES] = ps;
        }
        __syncthreads();

        // rank into s_srt
        for (int i = t; i < m; i += 512) {
            u32 p = s_ent[i];
            u32 pos = atomicAdd(&s_cur[p >> 17], 1u);
            s_srt[pos] = p & 0x1FFFFu;
        }
        __syncthreads();

        // accumulate: 8 lanes share one 128B x-row; 4-way unroll for MLP
        {
            u32 j = s_off[n0], j1 = s_off[n0 + 1];
            for (; j + 3 < j1; j += 4) {
                float4 xa = x4[(size_t)s_srt[j] * 8 + q];
                float4 xb = x4[(size_t)s_srt[j + 1] * 8 + q];
                float4 xc = x4[(size_t)s_srt[j + 2] * 8 + q];
                float4 xd = x4[(size_t)s_srt[j + 3] * 8 + q];
                a0.x += xa.x + xb.x + xc.x + xd.x;
                a0.y += xa.y + xb.y + xc.y + xd.y;
                a0.z += xa.z + xb.z + xc.z + xd.z;
                a0.w += xa.w + xb.w + xc.w + xd.w;
            }
            for (; j < j1; ++j) {
                float4 xa = x4[(size_t)s_srt[j] * 8 + q];
                a0.x += xa.x; a0.y += xa.y; a0.z += xa.z; a0.w += xa.w;
            }
            j = s_off[n0 + 64]; j1 = s_off[n0 + 65];
            for (; j + 3 < j1; j += 4) {
                float4 xa = x4[(size_t)s_srt[j] * 8 + q];
                float4 xb = x4[(size_t)s_srt[j + 1] * 8 + q];
                float4 xc = x4[(size_t)s_srt[j + 2] * 8 + q];
                float4 xd = x4[(size_t)s_srt[j + 3] * 8 + q];
                a1.x += xa.x + xb.x + xc.x + xd.x;
                a1.y += xa.y + xb.y + xc.y + xd.y;
                a1.z += xa.z + xb.z + xc.z + xd.z;
                a1.w += xa.w + xb.w + xc.w + xd.w;
            }
            for (; j < j1; ++j) {
                float4 xa = x4[(size_t)s_srt[j] * 8 + q];
                a1.x += xa.x; a1.y += xa.y; a1.z += xa.z; a1.w += xa.w;
            }
        }
        __syncthreads();
        subA = subB;
        baseA = s_base[subB];
    }

    // replay per-block overflow lists (normally all empty)
    if (s_has) {
        for (int sub = 0; sub < nsub; ++sub) {
            u32 n = ovfn[sub];
            for (u32 i = 0; i < n; ++i) {
                u32 ob = ovfb[((size_t)sub * OVFB + i) * 2 + 1];
                if (ob == (u32)b) {
                    u32 p = ovfb[((size_t)sub * OVFB + i) * 2];
                    u32 dl = p >> 17;
                    if (dl == (u32)n0 || dl == (u32)(n0 + 64)) {
                        float4 xv = x4[(size_t)(p & 0x1FFFFu) * 8 + q];
                        if (dl == (u32)n0) { a0.x += xv.x; a0.y += xv.y; a0.z += xv.z; a0.w += xv.w; }
                        else               { a1.x += xv.x; a1.y += xv.y; a1.z += xv.z; a1.w += xv.w; }
                    }
                }
            }
        }
    }

    float4* o4 = (float4*)out;
    if (node0 + n0 < n_nodes)      o4[(size_t)node0 * 8 + t] = a0;
    if (node0 + n0 + 64 < n_nodes) o4[(size_t)node0 * 8 + 512 + t] = a1;
}

// ---------------- fallback (round-1 atomic path) ----------------

__global__ void __launch_bounds__(256)
mp_zero_kernel(float* __restrict__ out, int n) {
    int i = blockIdx.x * blockDim.x + threadIdx.x;
    if (i < n) out[i] = 0.0f;
}

__global__ void __launch_bounds__(256)
mp_scatter_kernel(const float* __restrict__ x, const int* __restrict__ src,
                  const int* __restrict__ dst, float* __restrict__ out,
                  int n_edges) {
    int idx = blockIdx.x * blockDim.x + threadIdx.x;
    if (idx >= n_edges * 8) return;
    int e = idx >> 3;
    int c = idx & 7;
    const float4 v = *reinterpret_cast<const float4*>(x + (size_t)src[e] * D_FEAT + c * 4);
    float* o = out + (size_t)dst[e] * D_FEAT + c * 4;
    unsafeAtomicAdd(o + 0, v.x);
    unsafeAtomicAdd(o + 1, v.y);
    unsafeAtomicAdd(o + 2, v.z);
    unsafeAtomicAdd(o + 3, v.w);
}

// ==================== launch ====================

extern "C" void kernel_launch(void* const* d_in, const int* in_sizes, int n_in,
                              void* d_out, int out_size, void* d_ws, size_t ws_size,
                              hipStream_t stream) {
    const float* x = (const float*)d_in[0];
    const int* edge_index = (const int*)d_in[1];
    int n_edges = in_sizes[1] / 2;
    const int* src = edge_index;            // row 0: source j
    const int* dst = edge_index + n_edges;  // row 1: target i
    float* out = (float*)d_out;
    int n_nodes = out_size / D_FEAT;

    int nb = (n_nodes + BKT_NODES - 1) >> BKT_SHIFT;     // 782

    // dynamic LDS for scatter: nb*CAP stage + nb cursors
    size_t sc_lds = ((size_t)nb * CAP + nb) * sizeof(u32);   // 53.2 KB @ nb=782

    if (n_nodes <= (1 << 17) && sc_lds <= 64 * 1024) {
        const int ncand[3] = {512, 384, 256};
        for (int ci = 0; ci < 3; ++ci) {
            int nsub = ncand[ci];
            int chunk = (n_edges + nsub - 1) / nsub;
            size_t need = ((size_t)nsub * nb                      // cnt
                           + 512                                  // ovfn
                           + 2 * (size_t)nsub * OVFB              // ovfb
                           + (((size_t)nb * nsub) << CAPSH))      // bin (bucket-major)
                          * sizeof(u32);
            if (need > ws_size) continue;

            u32* cnt  = (u32*)d_ws;
            u32* ovfn = cnt + (size_t)nsub * nb;
            u32* ovfb = ovfn + 512;
            u32* bin  = ovfb + 2 * (size_t)nsub * OVFB;

            k_scatter5<<<nsub, 512, sc_lds, stream>>>(src, dst, cnt, bin, ovfb, ovfn,
                                                      n_edges, nb, nsub, chunk);
            k_gather5<<<nb, 512, 0, stream>>>(x, cnt, bin, ovfb, ovfn, out,
                                              n_nodes, nb, nsub);
            return;
        }
    }

    // last-resort: atomic path
    mp_zero_kernel<<<(out_size + 255) / 256, 256, 0, stream>>>(out, out_size);
    int total_thr = n_edges * 8;
    mp_scatter_kernel<<<(total_thr + 255) / 256, 256, 0, stream>>>(x, src, dst, out, n_edges);
}